// Round 9
// baseline (224.311 us; speedup 1.0000x reference)
//
#include <hip/hip_runtime.h>
#include <math.h>

// Problem constants
#define BATCH   16
#define CDIM    512
#define HWDIM   9216      // 96*96
#define NCLS    64
#define TILE    64
#define NTILES  144       // 9216/64
#define NCHUNK  16        // 512/32

// Output layout (floats): heatmap[16*9216], logits[16], loss[1], ip[16*64*9216]
#define LOGOFF  147456
#define LOSSOFF 147472
#define IPOFF   147473

// Workspace layout (floats)
#define WS_CC   0         // combined centers [128][512] fp32 (dead after pack)
#define WS_PH   0         // per-block heat sums [2304]  (reuses CC region)
#define WS_PC   2304      // per-block cluster sums [2304]
#define WS_S    65536     // s[64]
#define WS_AP   67904     // A-piece fragments: 16 chunks * 3p * 8mb * 64lane * 4 floats
#define WS_MIX  166208    // mix [64][512]

typedef __attribute__((ext_vector_type(8))) short bf16x8;
typedef __attribute__((ext_vector_type(4))) float f32x4;

__device__ __forceinline__ void split3(float v, float& h, float& m, float& l) {
  float hf = __uint_as_float(__float_as_uint(v) & 0xFFFF0000u);
  float r  = v - hf;                    // exact
  float mf = __uint_as_float(__float_as_uint(r) & 0xFFFF0000u);
  float r2 = r - mf;                    // exact
  float lf = __uint_as_float(__float_as_uint(r2) & 0xFFFF0000u);
  h = hf; m = mf; l = lf;
}

__device__ __forceinline__ unsigned packbf(float a, float b) {
  return (__float_as_uint(a) >> 16) | (__float_as_uint(b) & 0xFFFF0000u);
}

// ---------------------------------------------------------------------------
// prep1: a-normalized mix rows, centers copy, s[n]
// ---------------------------------------------------------------------------
__global__ __launch_bounds__(256) void prep1_kernel(
    const float* __restrict__ centers, const float* __restrict__ Aadj,
    const float* __restrict__ W_bc, const float* __restrict__ b_bc,
    float* __restrict__ ws) {
  __shared__ float a_n[NCLS];
  __shared__ float red[256];
  const int n = blockIdx.x;
  const int tid = threadIdx.x;

  if (tid < NCLS) a_n[tid] = Aadj[n * NCLS + tid] + (tid == n ? 1.0f : 0.0f);
  __syncthreads();
  if (tid == 0) {
    float ssum = 0.f;
    for (int w = 0; w < NCLS; ++w) ssum += a_n[w];
    red[0] = 1.0f / ssum;
  }
  __syncthreads();
  float inv = red[0];
  __syncthreads();
  if (tid < NCLS) a_n[tid] *= inv;
  __syncthreads();

  float p = 0.f;
  for (int c = tid; c < CDIM; c += 256) {
    float v = centers[n * CDIM + c];
    ws[WS_CC + n * CDIM + c] = v;
    float acc = 0.f;
    #pragma unroll 8
    for (int w = 0; w < NCLS; ++w) acc = fmaf(a_n[w], centers[w * CDIM + c], acc);
    ws[WS_MIX + n * CDIM + c] = 0.05f * v + 0.95f * acc;
    p = fmaf(W_bc[c], v, p);
  }
  red[tid] = p;
  __syncthreads();
  for (int st = 128; st > 0; st >>= 1) {
    if (tid < st) red[tid] += red[tid + st];
    __syncthreads();
  }
  if (tid == 0) ws[WS_S + n] = red[0] + b_bc[0];
}

// ---------------------------------------------------------------------------
// prep2: new_centers[n][o] = b_gcn[o] + sum_k W_gcn[o][k]*cat[k][n]
// ---------------------------------------------------------------------------
__global__ __launch_bounds__(256) void prep2_kernel(
    const float* __restrict__ W_gcn, const float* __restrict__ b_gcn,
    float* __restrict__ ws) {
  __shared__ float catT[128][65];
  const int tid = threadIdx.x;
  const int oo = tid >> 6, n = tid & 63;
  const int o = blockIdx.x * 4 + oo;
  const float* Wrow = W_gcn + (size_t)o * 1024;
  float acc = b_gcn[o];

  for (int k0 = 0; k0 < 1024; k0 += 128) {
    __syncthreads();
    const float* srcb = (k0 < 512) ? (ws + WS_CC + k0) : (ws + WS_MIX + (k0 - 512));
    #pragma unroll
    for (int i = 0; i < 32; ++i) {
      int idx = i * 256 + tid;
      int kk = idx & 127, n2 = idx >> 7;
      catT[kk][n2] = srcb[(size_t)n2 * CDIM + kk];
    }
    __syncthreads();
    #pragma unroll 16
    for (int kk = 0; kk < 128; ++kk)
      acc = fmaf(Wrow[k0 + kk], catT[kk][n], acc);
  }
  ws[WS_CC + (size_t)(NCLS + n) * CDIM + o] = acc;
}

// ---------------------------------------------------------------------------
// Pack: split CC into 3 bf16 pieces, fragment-linear per (chunk,p,mb,lane)
// ---------------------------------------------------------------------------
__global__ __launch_bounds__(256) void pack_kernel(float* __restrict__ ws) {
  const int gid = blockIdx.x * 256 + threadIdx.x;   // 8192 = 16c*8mb*64lane
  const int lane = gid & 63;
  const int mb = (gid >> 6) & 7;
  const int c = gid >> 9;
  const int row = mb * 16 + (lane & 15);
  const int kb = c * 32 + ((lane >> 4) & 3) * 8;
  const float* src = ws + WS_CC + (size_t)row * CDIM + kb;
  float e[8];
  *(float4*)&e[0] = *(const float4*)(src);
  *(float4*)&e[4] = *(const float4*)(src + 4);
  unsigned dh[4], dm[4], dl[4];
  #pragma unroll
  for (int d = 0; d < 4; ++d) {
    float h0, m0, l0, h1, m1, l1;
    split3(e[2 * d], h0, m0, l0);
    split3(e[2 * d + 1], h1, m1, l1);
    dh[d] = packbf(h0, h1); dm[d] = packbf(m0, m1); dl[d] = packbf(l0, l1);
  }
  const size_t base = WS_AP + (size_t)c * 6144 + (size_t)mb * 256 + (size_t)lane * 4;
  *(uint4*)(ws + base)        = make_uint4(dh[0], dh[1], dh[2], dh[3]);
  *(uint4*)(ws + base + 2048) = make_uint4(dm[0], dm[1], dm[2], dm[3]);
  *(uint4*)(ws + base + 4096) = make_uint4(dl[0], dl[1], dl[2], dl[3]);
}

// ---------------------------------------------------------------------------
// Main: MFMA split-bf16 dual GEMM, TILE=64 cols/block -> 4 blocks/CU.
// Wave w stages k-octet w and computes rows [16w,16w+16) ip + nip, all 64
// cols. B reg-staged 1-chunk lead into double-buffered LDS (12.25 KB LDS),
// A register-prefetched 1 chunk ahead, lgkm-only barrier, setprio on MFMA.
// ---------------------------------------------------------------------------
__global__ __launch_bounds__(256, 4) void main_kernel(
    const float* __restrict__ x, const float* __restrict__ gumbel,
    float* __restrict__ ws, float* __restrict__ out) {
  __shared__ char ldsmem[24576];          // 2 x 12288 B-piece buffers
  __shared__ float s_sh[NCLS];
  char* buf0 = ldsmem;
  char* buf1 = ldsmem + 12288;

  const int tid = threadIdx.x;
  const int w = tid >> 6, l = tid & 63;
  const int q = l >> 4, c15 = l & 15;
  const int tile = blockIdx.x, b = blockIdx.y;
  const int hw0 = tile * TILE;

  if (tid < NCLS) s_sh[tid] = ws[WS_S + tid];

  const float* xb = x + (size_t)b * CDIM * HWDIM;
  const float* pB = xb + (size_t)(w * 8) * HWDIM + hw0 + l;   // k = c*32 + w*8 + j
  const char* ap = (const char*)(ws + WS_AP);
  const int la16 = l * 16;

  f32x4 cip[4], cnp[4];
  #pragma unroll
  for (int i = 0; i < 4; ++i) {
    cip[i] = (f32x4){0.f, 0.f, 0.f, 0.f};
    cnp[i] = (f32x4){0.f, 0.f, 0.f, 0.f};
  }

  float bre[8];
  bf16x8 A0[5], A1[5];

#define LOAD_A(AS, c_) do {                                                   \
    const char* asrc = ap + (size_t)(c_) * 24576;                             \
    AS[0] = *(const bf16x8*)(asrc + w * 1024 + la16);                         \
    AS[1] = *(const bf16x8*)(asrc + 8192 + w * 1024 + la16);                  \
    AS[2] = *(const bf16x8*)(asrc + 16384 + w * 1024 + la16);                 \
    AS[3] = *(const bf16x8*)(asrc + (4 + w) * 1024 + la16);                   \
    AS[4] = *(const bf16x8*)(asrc + 8192 + (4 + w) * 1024 + la16);            \
  } while (0)

#define LOAD_B(c_) do {                                                       \
    const size_t koff = (size_t)(c_) * 32 * HWDIM;                            \
    _Pragma("unroll")                                                         \
    for (int j = 0; j < 8; ++j) bre[j] = pB[koff + (size_t)j * HWDIM];        \
  } while (0)

#define WRITE_B(WB) do {                                                      \
    unsigned dh[4], dm[4], dl[4];                                             \
    _Pragma("unroll")                                                         \
    for (int d = 0; d < 4; ++d) {                                             \
      float h0, m0, l0, h1, m1, l1;                                           \
      split3(bre[2 * d], h0, m0, l0);                                         \
      split3(bre[2 * d + 1], h1, m1, l1);                                     \
      dh[d] = packbf(h0, h1); dm[d] = packbf(m0, m1); dl[d] = packbf(l0, l1); \
    }                                                                         \
    char* basep = (WB) + (q * 1024 + w * 256 + c15 * 16);                     \
    *(uint4*)(basep)        = make_uint4(dh[0], dh[1], dh[2], dh[3]);         \
    *(uint4*)(basep + 4096) = make_uint4(dm[0], dm[1], dm[2], dm[3]);         \
    *(uint4*)(basep + 8192) = make_uint4(dl[0], dl[1], dl[2], dl[3]);         \
  } while (0)

#define LGKM_BARRIER() do {                                                   \
    asm volatile("s_waitcnt lgkmcnt(0)" ::: "memory");                        \
    __builtin_amdgcn_s_barrier();                                             \
    __builtin_amdgcn_sched_barrier(0);                                        \
  } while (0)

#define PHASE(RB, AC) do {                                                    \
    __builtin_amdgcn_s_setprio(1);                                            \
    _Pragma("unroll")                                                         \
    for (int nb = 0; nb < 4; ++nb) {                                          \
      bf16x8 bH = *(const bf16x8*)((RB) + nb * 1024 + la16);                  \
      bf16x8 bM = *(const bf16x8*)((RB) + 4096 + nb * 1024 + la16);           \
      bf16x8 bL = *(const bf16x8*)((RB) + 8192 + nb * 1024 + la16);           \
      cip[nb] = __builtin_amdgcn_mfma_f32_16x16x32_bf16(AC[0], bH, cip[nb], 0, 0, 0); \
      cip[nb] = __builtin_amdgcn_mfma_f32_16x16x32_bf16(AC[0], bM, cip[nb], 0, 0, 0); \
      cip[nb] = __builtin_amdgcn_mfma_f32_16x16x32_bf16(AC[1], bH, cip[nb], 0, 0, 0); \
      cip[nb] = __builtin_amdgcn_mfma_f32_16x16x32_bf16(AC[0], bL, cip[nb], 0, 0, 0); \
      cip[nb] = __builtin_amdgcn_mfma_f32_16x16x32_bf16(AC[1], bM, cip[nb], 0, 0, 0); \
      cip[nb] = __builtin_amdgcn_mfma_f32_16x16x32_bf16(AC[2], bH, cip[nb], 0, 0, 0); \
      cnp[nb] = __builtin_amdgcn_mfma_f32_16x16x32_bf16(AC[3], bH, cnp[nb], 0, 0, 0); \
      cnp[nb] = __builtin_amdgcn_mfma_f32_16x16x32_bf16(AC[3], bM, cnp[nb], 0, 0, 0); \
      cnp[nb] = __builtin_amdgcn_mfma_f32_16x16x32_bf16(AC[4], bH, cnp[nb], 0, 0, 0); \
    }                                                                         \
    __builtin_amdgcn_s_setprio(0);                                            \
  } while (0)

#define CHUNK(c_, RB, WB, AC, AN) do {                                        \
    if ((c_) + 1 < NCHUNK) {                                                  \
      LOAD_A(AN, (c_) + 1);                                                   \
      LOAD_B((c_) + 1);                                                       \
      __builtin_amdgcn_sched_barrier(0);                                      \
    }                                                                         \
    PHASE(RB, AC);                                                            \
    if ((c_) + 1 < NCHUNK) WRITE_B(WB);                                       \
    LGKM_BARRIER();                                                           \
  } while (0)

  // prologue: chunk 0 staged into buf0
  LOAD_A(A0, 0);
  LOAD_B(0);
  WRITE_B(buf0);
  LGKM_BARRIER();

  #pragma unroll 1
  for (int cc = 0; cc < NCHUNK; cc += 2) {
    CHUNK(cc, buf0, buf1, A0, A1);
    CHUNK(cc + 1, buf1, buf0, A1, A0);
  }

  // ---------------- epilogue ----------------
  float* pvv  = (float*)ldsmem;           // [4][64]
  int*   pvi  = (int*)(ldsmem + 1024);
  float* pnm  = (float*)(ldsmem + 2048);
  float* pns  = (float*)(ldsmem + 3072);
  float* m2   = (float*)(ldsmem + 4096);  // [64]
  float* hbuf = (float*)(ldsmem + 4352);
  float* cbuf = (float*)(ldsmem + 4608);

  const size_t bn = (size_t)b * NCLS;
  float* ipo = out + IPOFF;

  #pragma unroll
  for (int nb = 0; nb < 4; ++nb) {
    const int col = nb * 16 + c15;
    const int gcol = hw0 + col;
    float best = -1e30f; int bi = 0;
    #pragma unroll
    for (int r = 0; r < 4; ++r) {
      const int n = 16 * w + q * 4 + r;
      const size_t off = (bn + n) * HWDIM + gcol;
      const float v = cip[nb][r];
      ipo[off] = v;
      const float t = v + gumbel[off];
      if (t > best) { best = t; bi = n; }   // strict > keeps lowest n in-lane
    }
    #pragma unroll
    for (int mk = 16; mk <= 32; mk <<= 1) {
      float ov = __shfl_xor(best, mk);
      int   oi = __shfl_xor(bi, mk);
      if (ov > best || (ov == best && oi < bi)) { best = ov; bi = oi; }
    }
    float mx = -1e30f;
    #pragma unroll
    for (int r = 0; r < 4; ++r) mx = fmaxf(mx, cnp[nb][r]);
    #pragma unroll
    for (int mk = 16; mk <= 32; mk <<= 1) mx = fmaxf(mx, __shfl_xor(mx, mk));
    if (q == 0) {
      pvv[w * 64 + col] = best;
      pvi[w * 64 + col] = bi;
      pnm[w * 64 + col] = mx;
    }
  }
  __syncthreads();

  if (tid < 64) {
    float v = pvv[tid]; int i = pvi[tid];
    #pragma unroll
    for (int ww = 1; ww < 4; ++ww) {
      float v2 = pvv[ww * 64 + tid]; int i2 = pvi[ww * 64 + tid];
      if (v2 > v || (v2 == v && i2 < i)) { v = v2; i = i2; }
    }
    float h = s_sh[i];
    hbuf[tid] = h;
    out[(size_t)b * HWDIM + hw0 + tid] = h;
    float m = pnm[tid];
    #pragma unroll
    for (int ww = 1; ww < 4; ++ww) m = fmaxf(m, pnm[ww * 64 + tid]);
    m2[tid] = m;
  }
  __syncthreads();

  #pragma unroll
  for (int nb = 0; nb < 4; ++nb) {
    const int col = nb * 16 + c15;
    const float mm = m2[col];
    float s = __expf(cnp[nb][0] - mm) + __expf(cnp[nb][1] - mm)
            + __expf(cnp[nb][2] - mm) + __expf(cnp[nb][3] - mm);
    s += __shfl_xor(s, 16);
    s += __shfl_xor(s, 32);
    if (q == 0) pns[w * 64 + col] = s;
  }
  __syncthreads();

  if (tid < 64) {
    float S = pns[tid] + pns[64 + tid] + pns[128 + tid] + pns[192 + tid];
    cbuf[tid] = 1.0f / S;
  }
  __syncthreads();

  if (tid < 64) {
    float hs = hbuf[tid];
    float cs = cbuf[tid];
    #pragma unroll
    for (int o = 32; o > 0; o >>= 1) {
      hs += __shfl_down(hs, o);
      cs += __shfl_down(cs, o);
    }
    if (tid == 0) {
      ws[WS_PH + b * NTILES + tile] = hs;
      ws[WS_PC + b * NTILES + tile] = cs;
    }
  }
#undef LOAD_A
#undef LOAD_B
#undef WRITE_B
#undef PHASE
#undef CHUNK
#undef LGKM_BARRIER
}

// ---------------------------------------------------------------------------
// Finish: logits + cluster_loss from per-block partials (deterministic order)
// ---------------------------------------------------------------------------
__global__ __launch_bounds__(256) void finish_kernel(
    const float* __restrict__ ws, float* __restrict__ out) {
  __shared__ double sred[256];
  const int tid = threadIdx.x;
  {
    int bb = tid >> 4, lane = tid & 15;
    double s = 0.0;
    for (int t = lane; t < NTILES; t += 16) s += (double)ws[WS_PH + bb * NTILES + t];
    #pragma unroll
    for (int o = 8; o > 0; o >>= 1) s += __shfl_down(s, o, 16);
    if (lane == 0) out[LOGOFF + bb] = (float)(s / (double)HWDIM);
  }
  double c = 0.0;
  for (int i = tid; i < BATCH * NTILES; i += 256) c += (double)ws[WS_PC + i];
  sred[tid] = c;
  __syncthreads();
  for (int st = 128; st > 0; st >>= 1) {
    if (tid < st) sred[tid] += sred[tid + st];
    __syncthreads();
  }
  if (tid == 0) out[LOSSOFF] = (float)(-sred[0] / (double)(BATCH * HWDIM));
}

// ---------------------------------------------------------------------------
extern "C" void kernel_launch(void* const* d_in, const int* in_sizes, int n_in,
                              void* d_out, int out_size, void* d_ws, size_t ws_size,
                              hipStream_t stream) {
  const float* x       = (const float*)d_in[0];
  const float* centers = (const float*)d_in[1];
  const float* Aadj    = (const float*)d_in[2];
  const float* gumbel  = (const float*)d_in[3];
  const float* W_bc    = (const float*)d_in[4];
  const float* b_bc    = (const float*)d_in[5];
  const float* W_gcn   = (const float*)d_in[6];
  const float* b_gcn   = (const float*)d_in[7];
  float* out = (float*)d_out;
  float* ws  = (float*)d_ws;

  hipLaunchKernelGGL(prep1_kernel, dim3(NCLS), dim3(256), 0, stream,
                     centers, Aadj, W_bc, b_bc, ws);
  hipLaunchKernelGGL(prep2_kernel, dim3(128), dim3(256), 0, stream,
                     W_gcn, b_gcn, ws);
  hipLaunchKernelGGL(pack_kernel, dim3(32), dim3(256), 0, stream, ws);
  hipLaunchKernelGGL(main_kernel, dim3(NTILES, BATCH), dim3(256), 0, stream,
                     x, gumbel, ws, out);
  hipLaunchKernelGGL(finish_kernel, dim3(1), dim3(256), 0, stream, ws, out);
}